// Round 9
// baseline (239.604 us; speedup 1.0000x reference)
//
#include <hip/hip_runtime.h>

#define NN 50000
#define NE 800000
#define NB 391      // ceil(NN/128)
#define TOTF 114688 // frag elems: W1 (8kc*8nt*64*8=32768) + 5 matrices * 16384

typedef unsigned short u16;
typedef unsigned int u32;
typedef __attribute__((ext_vector_type(8))) short s8v;   // 8 bf16 = 4 VGPRs (MFMA A/B frag)
typedef __attribute__((ext_vector_type(4))) float f4v;   // MFMA C/D frag

// split fp32 into hi (truncated bf16) + lo (bf16 of remainder): f ~= hi + lo, err ~2^-16*|f|
__device__ __forceinline__ void split2(float f, u16& h, u16& lo) {
    u32 u = __float_as_uint(f);
    h = (u16)(u >> 16);
    float r = f - __uint_as_float(u & 0xFFFF0000u);   // exact
    lo = (u16)(__float_as_uint(r) >> 16);
}

// ---- in-degree mask scatter: mask[dst[e]] = 1 ----
__global__ void mask_scatter_k(const int* __restrict__ dst, float* __restrict__ mask) {
    int i = blockIdx.x * blockDim.x + threadIdx.x;
    if (i < NE) mask[dst[i]] = 1.0f;
}

// ---- convert the 6 weight matrices into B-fragment-ordered split-bf16 arrays ----
// frag elem(idx): j=idx&7, l=(idx>>3)&63, nt=(idx>>9)&7, kc=idx>>12
//   -> W[kc*32 + (l>>4)*8 + j][nt*16 + (l&15)]
__global__ void prep_w_k(const float* __restrict__ W1, const float* __restrict__ W2,
                         const float* __restrict__ Wv, const float* __restrict__ Wo,
                         u16* __restrict__ fh, u16* __restrict__ fl) {
    int idx = blockIdx.x * 256 + threadIdx.x;
    if (idx >= TOTF) return;
    const float* W;
    int local;
    if (idx < 32768) { W = W1; local = idx; }
    else {
        int t = idx - 32768;
        int m = t >> 14;
        local = t & 16383;
        if (m == 0) W = W2;
        else if (m == 1) W = Wv;
        else if (m == 2) W = Wo;
        else if (m == 3) W = Wv + 16384;
        else W = Wo + 16384;
    }
    int j = local & 7, l = (local >> 3) & 63, nt = (local >> 9) & 7, kc = local >> 12;
    int k = kc * 32 + ((l >> 4) << 3) + j;
    int n = nt * 16 + (l & 15);
    u16 h, lo;
    split2(W[k * 128 + n], h, lo);
    fh[idx] = h;
    fl[idx] = lo;
}

// ---- reduce per-block stat partials: st[c] = sum_b pst[b][c], c in [0,256) ----
__global__ __launch_bounds__(64)
void redstats_k(const float* __restrict__ pst, float* __restrict__ st) {
    int c = blockIdx.x;
    float s = 0.f;
    for (int b = threadIdx.x; b < NB; b += 64) s += pst[(size_t)b * 256 + c];
    s += __shfl_xor(s, 1);  s += __shfl_xor(s, 2);  s += __shfl_xor(s, 4);
    s += __shfl_xor(s, 8);  s += __shfl_xor(s, 16); s += __shfl_xor(s, 32);
    if (threadIdx.x == 0) st[c] = s;
}

// ---- MFMA GEMM: 4 waves x 32 rows each (128-row block), full 128 cols per wave ----
// B-frags shared across both 16-row tiles in-register; K in passes of 128.
template<int KC, int FOLD, int STATS>
__global__ __launch_bounds__(256, 2)
void mgemm_k(const float* __restrict__ A,
             const u16* __restrict__ fh, const u16* __restrict__ fl,
             const float* __restrict__ bias,
             const float* __restrict__ fst,        // prev-layer stats [256] (sum|sq)
             const float* __restrict__ fg, const float* __restrict__ fbe,
             float* __restrict__ pst,              // per-block partials [NB][256]
             float* __restrict__ C) {
    constexpr int K = KC * 32;
    constexpr int KP = KC / 4;       // 128-wide K passes
    __shared__ __align__(16) u16 Ah[128][136];
    __shared__ __align__(16) u16 Al[128][136];
    __shared__ float scl[128], shf[128];
    const int tid = threadIdx.x;
    const int l = tid & 63, w = tid >> 6;        // wave 0..3 owns rows 32w..32w+31
    const int q = l >> 4, cc = l & 15;
    const int row0 = blockIdx.x * 128;

    if (FOLD) {
        if (tid < 128) {
            float mean = fst[tid] * (1.0f / NN);
            float var = fst[128 + tid] * (1.0f / NN) - mean * mean;   // biased
            float rstd = rsqrtf(var + 1e-5f);
            float ga = fg[tid] * rstd;
            scl[tid] = ga;
            shf[tid] = fbe[tid] - mean * ga;
        }
        __syncthreads();
    }

    f4v zf = {0.f, 0.f, 0.f, 0.f};
    f4v acc0[8], acc1[8];
#pragma unroll
    for (int nt = 0; nt < 8; ++nt) { acc0[nt] = zf; acc1[nt] = zf; }

    for (int p = 0; p < KP; ++p) {
        // wave-local staging: own 32 rows x 128 k, fp32 -> (bn+relu) -> hi/lo planes
#pragma unroll
        for (int it = 0; it < 16; ++it) {
            int lin = it * 64 + l;               // 0..1023
            int r = lin >> 5;                    // 0..31
            int c4 = (lin & 31) * 4;
            int gr = row0 + 32 * w + r; if (gr > NN - 1) gr = NN - 1;
            float4 f = *(const float4*)(A + (size_t)gr * K + p * 128 + c4);
            float v[4] = {f.x, f.y, f.z, f.w};
            if (FOLD) {
#pragma unroll
                for (int m = 0; m < 4; ++m) {
                    float t = v[m] * scl[c4 + m] + shf[c4 + m];
                    v[m] = t > 0.f ? t : 0.f;
                }
            }
            ushort4 uh, ul;
            split2(v[0], uh.x, ul.x); split2(v[1], uh.y, ul.y);
            split2(v[2], uh.z, ul.z); split2(v[3], uh.w, ul.w);
            *(ushort4*)&Ah[32 * w + r][c4] = uh;
            *(ushort4*)&Al[32 * w + r][c4] = ul;
        }
        // no barrier: all rows wave-local, DS ops in-order per wave
#pragma unroll
        for (int kc = 0; kc < 4; ++kc) {
            int kcg = p * 4 + kc;
            s8v ah0 = *(const s8v*)&Ah[32 * w + cc][kc * 32 + q * 8];
            s8v al0 = *(const s8v*)&Al[32 * w + cc][kc * 32 + q * 8];
            s8v ah1 = *(const s8v*)&Ah[32 * w + 16 + cc][kc * 32 + q * 8];
            s8v al1 = *(const s8v*)&Al[32 * w + 16 + cc][kc * 32 + q * 8];
#pragma unroll
            for (int nt = 0; nt < 8; ++nt) {
                const int fo = kcg * 4096 + nt * 512 + l * 8;
                s8v bh = *(const s8v*)(fh + fo);
                s8v bl = *(const s8v*)(fl + fo);
                acc0[nt] = __builtin_amdgcn_mfma_f32_16x16x32_bf16(ah0, bh, acc0[nt], 0, 0, 0);
                acc0[nt] = __builtin_amdgcn_mfma_f32_16x16x32_bf16(ah0, bl, acc0[nt], 0, 0, 0);
                acc0[nt] = __builtin_amdgcn_mfma_f32_16x16x32_bf16(al0, bh, acc0[nt], 0, 0, 0);
                acc1[nt] = __builtin_amdgcn_mfma_f32_16x16x32_bf16(ah1, bh, acc1[nt], 0, 0, 0);
                acc1[nt] = __builtin_amdgcn_mfma_f32_16x16x32_bf16(ah1, bl, acc1[nt], 0, 0, 0);
                acc1[nt] = __builtin_amdgcn_mfma_f32_16x16x32_bf16(al1, bh, acc1[nt], 0, 0, 0);
            }
        }
    }

    // epilogue: D[row=quad*4+r][col=lane&15] per 16-col tile; raw store + stat partials
    float ps[8], pq[8];
#pragma unroll
    for (int nt = 0; nt < 8; ++nt) { ps[nt] = 0.f; pq[nt] = 0.f; }
#pragma unroll
    for (int nt = 0; nt < 8; ++nt) {
        int col = nt * 16 + cc;
        float bb = bias[col];
#pragma unroll
        for (int rt = 0; rt < 2; ++rt) {
#pragma unroll
            for (int r = 0; r < 4; ++r) {
                int gr = row0 + 32 * w + 16 * rt + q * 4 + r;
                float val = (rt ? acc1[nt][r] : acc0[nt][r]) + bb;
                if (gr < NN) {
                    C[(size_t)gr * 128 + col] = val;
                    if (STATS) { ps[nt] += val; pq[nt] += val * val; }
                }
            }
        }
    }
    if (STATS) {
        __syncthreads();                          // all LDS reads done: reuse Ah as wred
        float* wredS = (float*)&Ah[0][0];         // [4][128]
        float* wredQ = wredS + 512;               // [4][128]
#pragma unroll
        for (int nt = 0; nt < 8; ++nt) {
            ps[nt] += __shfl_xor(ps[nt], 16); ps[nt] += __shfl_xor(ps[nt], 32);
            pq[nt] += __shfl_xor(pq[nt], 16); pq[nt] += __shfl_xor(pq[nt], 32);
        }
        if (l < 16) {
#pragma unroll
            for (int nt = 0; nt < 8; ++nt) {
                wredS[w * 128 + nt * 16 + l] = ps[nt];
                wredQ[w * 128 + nt * 16 + l] = pq[nt];
            }
        }
        __syncthreads();
        {                                         // one coalesced 1KB record per block
            int c = tid & 127;
            const float* src = (tid < 128) ? wredS : wredQ;
            pst[(size_t)blockIdx.x * 256 + tid] =
                src[c] + src[128 + c] + src[256 + c] + src[384 + c];
        }
    }
}

// ---- mega: bn2+relu -> (.@Wv0+bv0)*mask -> relu(.@Wo0+bo0) -> (.@Wv1+bv1)*mask
//            -> relu(.@Wo1+bo1) -> out.  4 waves x 32 wave-local rows: no stage barriers.
__global__ __launch_bounds__(256, 2)
void mmega_k(const float* __restrict__ X,
             const u16* __restrict__ fh, const u16* __restrict__ fl,   // Wv0 frag base
             const float* __restrict__ bv, const float* __restrict__ bo,
             const float* __restrict__ fst,
             const float* __restrict__ fg, const float* __restrict__ fbe,
             const float* __restrict__ mask, float* __restrict__ out) {
    __shared__ __align__(16) u16 Ah[128][136];
    __shared__ __align__(16) u16 Al[128][136];
    __shared__ float scl[128], shf[128];
    const int tid = threadIdx.x;
    const int l = tid & 63, w = tid >> 6;
    const int q = l >> 4, cc = l & 15;
    const int row0 = blockIdx.x * 128;

    if (tid < 128) {
        float mean = fst[tid] * (1.0f / NN);
        float var = fst[128 + tid] * (1.0f / NN) - mean * mean;
        float rstd = rsqrtf(var + 1e-5f);
        float ga = fg[tid] * rstd;
        scl[tid] = ga;
        shf[tid] = fbe[tid] - mean * ga;
    }
    __syncthreads();

    float rm[2][4];
#pragma unroll
    for (int rt = 0; rt < 2; ++rt)
#pragma unroll
        for (int r = 0; r < 4; ++r) {
            int gr = row0 + 32 * w + 16 * rt + q * 4 + r;
            rm[rt][r] = (gr < NN) ? mask[gr] : 0.f;
        }

    // wave-local staging of relu(bn2(X)) into split planes
#pragma unroll
    for (int it = 0; it < 16; ++it) {
        int lin = it * 64 + l;
        int r = lin >> 5;
        int c4 = (lin & 31) * 4;
        int gr = row0 + 32 * w + r; if (gr > NN - 1) gr = NN - 1;
        float4 f = *(const float4*)(X + (size_t)gr * 128 + c4);
        float v[4] = {f.x, f.y, f.z, f.w};
#pragma unroll
        for (int m = 0; m < 4; ++m) {
            float t = v[m] * scl[c4 + m] + shf[c4 + m];
            v[m] = t > 0.f ? t : 0.f;
        }
        ushort4 uh, ul;
        split2(v[0], uh.x, ul.x); split2(v[1], uh.y, ul.y);
        split2(v[2], uh.z, ul.z); split2(v[3], uh.w, ul.w);
        *(ushort4*)&Ah[32 * w + r][c4] = uh;
        *(ushort4*)&Al[32 * w + r][c4] = ul;
    }

    f4v zf = {0.f, 0.f, 0.f, 0.f};
    for (int s = 0; s < 4; ++s) {
        const u16* WH = fh + s * 16384;     // Wv0, Wo0, Wv1, Wo1 consecutive
        const u16* WL = fl + s * 16384;
        const float* bp = (s == 0) ? bv : (s == 1) ? bo : (s == 2) ? (bv + 128) : (bo + 128);

        f4v acc0[8], acc1[8];
#pragma unroll
        for (int nt = 0; nt < 8; ++nt) { acc0[nt] = zf; acc1[nt] = zf; }
#pragma unroll
        for (int kc = 0; kc < 4; ++kc) {
            s8v ah0 = *(const s8v*)&Ah[32 * w + cc][kc * 32 + q * 8];
            s8v al0 = *(const s8v*)&Al[32 * w + cc][kc * 32 + q * 8];
            s8v ah1 = *(const s8v*)&Ah[32 * w + 16 + cc][kc * 32 + q * 8];
            s8v al1 = *(const s8v*)&Al[32 * w + 16 + cc][kc * 32 + q * 8];
#pragma unroll
            for (int nt = 0; nt < 8; ++nt) {
                const int fo = kc * 4096 + nt * 512 + l * 8;
                s8v bh = *(const s8v*)(WH + fo);
                s8v bl = *(const s8v*)(WL + fo);
                acc0[nt] = __builtin_amdgcn_mfma_f32_16x16x32_bf16(ah0, bh, acc0[nt], 0, 0, 0);
                acc0[nt] = __builtin_amdgcn_mfma_f32_16x16x32_bf16(ah0, bl, acc0[nt], 0, 0, 0);
                acc0[nt] = __builtin_amdgcn_mfma_f32_16x16x32_bf16(al0, bh, acc0[nt], 0, 0, 0);
                acc1[nt] = __builtin_amdgcn_mfma_f32_16x16x32_bf16(ah1, bh, acc1[nt], 0, 0, 0);
                acc1[nt] = __builtin_amdgcn_mfma_f32_16x16x32_bf16(ah1, bl, acc1[nt], 0, 0, 0);
                acc1[nt] = __builtin_amdgcn_mfma_f32_16x16x32_bf16(al1, bh, acc1[nt], 0, 0, 0);
            }
        }

        if (s == 3) {
#pragma unroll
            for (int nt = 0; nt < 8; ++nt) {
                int col = nt * 16 + cc;
                float bb = bp[col];
#pragma unroll
                for (int rt = 0; rt < 2; ++rt)
#pragma unroll
                    for (int r = 0; r < 4; ++r) {
                        int gr = row0 + 32 * w + 16 * rt + q * 4 + r;
                        if (gr < NN)
                            out[(size_t)gr * 128 + col] =
                                fmaxf((rt ? acc1[nt][r] : acc0[nt][r]) + bb, 0.f);
                    }
            }
        } else {
            // wave-local rows: this wave's DS reads (in-order) precede these writes
#pragma unroll
            for (int nt = 0; nt < 8; ++nt) {
                int col = nt * 16 + cc;
                float bb = bp[col];
#pragma unroll
                for (int rt = 0; rt < 2; ++rt)
#pragma unroll
                    for (int r = 0; r < 4; ++r) {
                        int rl = 32 * w + 16 * rt + q * 4 + r;
                        float val = (rt ? acc1[nt][r] : acc0[nt][r]) + bb;
                        val = (s == 1) ? fmaxf(val, 0.f) : val * rm[rt][r];
                        u16 h, lo; split2(val, h, lo);
                        Ah[rl][col] = h;
                        Al[rl][col] = lo;
                    }
            }
        }
    }
}

extern "C" void kernel_launch(void* const* d_in, const int* in_sizes, int n_in,
                              void* d_out, int out_size, void* d_ws, size_t ws_size,
                              hipStream_t stream) {
    const float* x   = (const float*)d_in[0];
    const int*   ei  = (const int*)d_in[1];
    const float* W1  = (const float*)d_in[2];
    const float* b1  = (const float*)d_in[3];
    const float* g1  = (const float*)d_in[4];
    const float* be1 = (const float*)d_in[5];
    const float* W2  = (const float*)d_in[6];
    const float* b2  = (const float*)d_in[7];
    const float* g2  = (const float*)d_in[8];
    const float* be2 = (const float*)d_in[9];
    // Wq/bq (10,11), Wk/bk (12,13) cancel: V gathered at dst => segment softmax sums to 1.
    const float* Wv  = (const float*)d_in[14];
    const float* bv  = (const float*)d_in[15];
    const float* Wo  = (const float*)d_in[16];
    const float* bo  = (const float*)d_in[17];

    float* out = (float*)d_out;

    char* ws = (char*)d_ws;
    float* buf  = (float*)(ws);                    // 25.6 MB raw x@W1+b1
    float* mask = (float*)(ws + 25600000);         // 200 KB
    float* st1  = (float*)(ws + 25800704);         // 1 KB (sum|sq layer1)
    float* st2  = st1 + 256;                       // 1 KB (layer2)
    u16*   fH   = (u16*)(ws + 25804800);           // 229 KB frag hi
    u16*   fL   = fH + TOTF;                       // 229 KB frag lo
    float* pst  = (float*)(ws + 26263552);         // NB*256*4 = 400 KB partials (reused)

    hipMemsetAsync(mask, 0, NN * sizeof(float), stream);
    mask_scatter_k<<<dim3((NE + 255) / 256), dim3(256), 0, stream>>>(ei + NE, mask);
    prep_w_k<<<dim3((TOTF + 255) / 256), dim3(256), 0, stream>>>(W1, W2, Wv, Wo, fH, fL);

    dim3 gg(NB), bb(256);
    // enc1: buf = x@W1+b1 (raw) + stat partials
    mgemm_k<8, 0, 1><<<gg, bb, 0, stream>>>(x, fH, fL, b1,
                                            nullptr, nullptr, nullptr, pst, buf);
    redstats_k<<<dim3(256), dim3(64), 0, stream>>>(pst, st1);
    // enc2: out = relu(bn1(buf))@W2+b2 (raw) + stat partials
    mgemm_k<4, 1, 1><<<gg, bb, 0, stream>>>(buf, fH + 32768, fL + 32768, b2,
                                            st1, g1, be1, pst, out);
    redstats_k<<<dim3(256), dim3(64), 0, stream>>>(pst, st2);
    // attention chain (collapsed), in-place on d_out
    mmega_k<<<gg, bb, 0, stream>>>(out, fH + 49152, fL + 49152, bv, bo,
                                   st2, g2, be2, mask, out);
}